// Round 4
// baseline (1171.906 us; speedup 1.0000x reference)
//
#include <hip/hip_runtime.h>
#include <cstdint>
#include <cstddef>

// ---------------------------------------------------------------------------
// ASD_RNN round 4: persistent LSTM with distributed-flag barrier + operand-
// swapped MFMA (no gate LDS remap), bf16 xg with pre-remapped Wx columns.
// B=64, S=64, F_IN=2048, H=512, 4H=2048, P2=20.
// ---------------------------------------------------------------------------

typedef __attribute__((ext_vector_type(8))) short short8;
typedef __attribute__((ext_vector_type(4))) float f32x4;

__device__ __forceinline__ ushort f2bf(float x) {
    uint32_t u = __float_as_uint(x);
    return (ushort)((u + 0x7FFF + ((u >> 16) & 1)) >> 16);   // RNE
}
__device__ __forceinline__ float bf2f(ushort u) {
    return __uint_as_float(((uint32_t)u) << 16);
}
__device__ __forceinline__ float sigm(float x) { return 1.f / (1.f + expf(-x)); }
__device__ __forceinline__ float tanh_fast(float x) { return 2.f / (1.f + expf(-2.f * x)) - 1.f; }

// fp32 -> bf16 elementwise (4 elems/thread)
__global__ __launch_bounds__(256) void k_f32_to_bf16(const float* __restrict__ in,
                                                     ushort* __restrict__ out) {
    int i = blockIdx.x * 256 + threadIdx.x;
    float4 v = ((const float4*)in)[i];
    ushort4 o;
    o.x = f2bf(v.x); o.y = f2bf(v.y); o.z = f2bf(v.z); o.w = f2bf(v.w);
    ((ushort4*)out)[i] = o;
}

// bxh[n'] = bx[n] + bh[n], n' = (n&511)*4 | (n>>9). grid 8 x 256.
__global__ __launch_bounds__(256) void k_bias(const float* __restrict__ bx,
                                              const float* __restrict__ bh,
                                              float* __restrict__ bxh) {
    int n = blockIdx.x * 256 + threadIdx.x;
    int np = ((n & 511) << 2) | (n >> 9);
    bxh[np] = bx[n] + bh[n];
}

// in [R][C] fp32 -> out [C][R] bf16, 32x32 LDS tiles. grid (C/32, R/32)
// remap!=0: output row n remapped to ((n&511)<<2)|(n>>9)  (j*4+gate order)
__global__ __launch_bounds__(256) void k_transpose_bf16(const float* __restrict__ in,
                                                        ushort* __restrict__ out,
                                                        int R, int C, int remap) {
    __shared__ float t[32][33];
    int r0 = blockIdx.y * 32, c0 = blockIdx.x * 32;
    int rr = threadIdx.x >> 3, cc = (threadIdx.x & 7) * 4;
    float4 v = *(const float4*)(in + (size_t)(r0 + rr) * C + c0 + cc);
    t[rr][cc + 0] = v.x; t[rr][cc + 1] = v.y; t[rr][cc + 2] = v.z; t[rr][cc + 3] = v.w;
    __syncthreads();
    ushort4 o;
    o.x = f2bf(t[cc + 0][rr]);
    o.y = f2bf(t[cc + 1][rr]);
    o.z = f2bf(t[cc + 2][rr]);
    o.w = f2bf(t[cc + 3][rr]);
    int n = c0 + rr;
    int np = remap ? (((n & 511) << 2) | (n >> 9)) : n;
    *(ushort4*)(out + (size_t)np * R + r0 + cc) = o;
}

// bf16 MFMA GEMM: C[M,N] = A[M,K] @ Bt[N,K]^T. 128x128 tile, 4 waves of 64x64.
// mode 0: fuse (bf16 [M][512]) = relu(acc+bias0[n]) + cat_emb[category[m>>6]][n]
// mode 1: xg (bf16 [s][b][n]) = acc + bias0[n]; m=b*64+s (n axis pre-remapped to n')
__global__ __launch_bounds__(256) void k_gemm_mfma(
    const ushort* __restrict__ A, const ushort* __restrict__ Bt,
    int M, int N, int K,
    const float* __restrict__ bias0,
    const float* __restrict__ cat_emb, const int* __restrict__ category,
    void* __restrict__ Cout, int mode)
{
    __shared__ ushort As[128][40];
    __shared__ ushort Bs[128][40];
    const int tid = threadIdx.x;
    const int lane = tid & 63, w = tid >> 6;
    const int quad = lane >> 4, l16 = lane & 15;
    const int m0 = blockIdx.y * 128, n0 = blockIdx.x * 128;
    const int wm = (w & 1) * 64, wn = (w >> 1) * 64;

    f32x4 acc[4][4] = {};
    const int lr = tid >> 2;
    const int lc = (tid & 3) * 8;

    for (int k0 = 0; k0 < K; k0 += 32) {
        uint4 a0 = *(const uint4*)(A + (size_t)(m0 + lr) * K + k0 + lc);
        uint4 a1 = *(const uint4*)(A + (size_t)(m0 + 64 + lr) * K + k0 + lc);
        uint4 b0 = *(const uint4*)(Bt + (size_t)(n0 + lr) * K + k0 + lc);
        uint4 b1 = *(const uint4*)(Bt + (size_t)(n0 + 64 + lr) * K + k0 + lc);
        __syncthreads();
        *(uint4*)&As[lr][lc] = a0;
        *(uint4*)&As[64 + lr][lc] = a1;
        *(uint4*)&Bs[lr][lc] = b0;
        *(uint4*)&Bs[64 + lr][lc] = b1;
        __syncthreads();
        short8 af[4], bf[4];
#pragma unroll
        for (int i = 0; i < 4; ++i) af[i] = *(const short8*)&As[wm + i * 16 + l16][quad * 8];
#pragma unroll
        for (int j = 0; j < 4; ++j) bf[j] = *(const short8*)&Bs[wn + j * 16 + l16][quad * 8];
#pragma unroll
        for (int i = 0; i < 4; ++i)
#pragma unroll
            for (int j = 0; j < 4; ++j)
                acc[i][j] = __builtin_amdgcn_mfma_f32_16x16x32_bf16(af[i], bf[j], acc[i][j], 0, 0, 0);
    }

    if (mode == 0) {
        ushort* C = (ushort*)Cout;
#pragma unroll
        for (int i = 0; i < 4; ++i) {
            int mbase = m0 + wm + i * 16 + quad * 4;
#pragma unroll
            for (int r = 0; r < 4; ++r) {
                int m = mbase + r;
                const float* ce = cat_emb + category[m >> 6] * 512;
#pragma unroll
                for (int j = 0; j < 4; ++j) {
                    int n = n0 + wn + j * 16 + l16;
                    float v = fmaxf(acc[i][j][r] + bias0[n], 0.f) + ce[n];
                    C[(size_t)m * 512 + n] = f2bf(v);
                }
            }
        }
    } else {
        ushort* C = (ushort*)Cout;
        float bb[4];
#pragma unroll
        for (int j = 0; j < 4; ++j) bb[j] = bias0[n0 + wn + j * 16 + l16];
#pragma unroll
        for (int i = 0; i < 4; ++i) {
            int mbase = m0 + wm + i * 16 + quad * 4;
#pragma unroll
            for (int r = 0; r < 4; ++r) {
                int m = mbase + r;
                int s = m & 63, b = m >> 6;
                ushort* crow = C + ((size_t)(s * 64 + b)) * 2048;
#pragma unroll
                for (int j = 0; j < 4; ++j)
                    crow[n0 + wn + j * 16 + l16] = f2bf(acc[i][j][r] + bb[j]);
            }
        }
    }
}

// dots[bs][p] = v_bf16[bs][:] . proto_bf[p][:] (proto padded to 32 rows)
__global__ __launch_bounds__(256) void k_dot(const ushort* __restrict__ v_bf,
                                             const ushort* __restrict__ proto_bf,
                                             float* __restrict__ dots)
{
    const int tid = threadIdx.x;
    const int lane = tid & 63, w = tid >> 6;
    const int quad = lane >> 4, l16 = lane & 15;
    const int r0 = blockIdx.x * 64 + w * 16;

    f32x4 acc[2] = {};
    const ushort* arow = v_bf + (size_t)(r0 + l16) * 2048 + quad * 8;
    const ushort* b0p = proto_bf + (size_t)l16 * 2048 + quad * 8;
    const ushort* b1p = proto_bf + (size_t)(16 + l16) * 2048 + quad * 8;
#pragma unroll 8
    for (int kk = 0; kk < 64; ++kk) {
        short8 af = *(const short8*)(arow + kk * 32);
        short8 bf0 = *(const short8*)(b0p + kk * 32);
        short8 bf1 = *(const short8*)(b1p + kk * 32);
        acc[0] = __builtin_amdgcn_mfma_f32_16x16x32_bf16(af, bf0, acc[0], 0, 0, 0);
        acc[1] = __builtin_amdgcn_mfma_f32_16x16x32_bf16(af, bf1, acc[1], 0, 0, 0);
    }
#pragma unroll
    for (int t = 0; t < 2; ++t)
#pragma unroll
        for (int r = 0; r < 4; ++r)
            dots[(size_t)(r0 + quad * 4 + r) * 32 + t * 16 + l16] = acc[t][r];
}

// per-row |v|^2 and gate-logit partials. grid 1024 blocks x 4 rows.
__global__ __launch_bounds__(256) void k_rowstats(const float* __restrict__ v_feat,
                                                  const float* __restrict__ W_gate,
                                                  float* __restrict__ n2,
                                                  float* __restrict__ g_logit)
{
    const int lane = threadIdx.x & 63, w = threadIdx.x >> 6;
    const int bs = blockIdx.x * 4 + w;
    const float* vr = v_feat + (size_t)bs * 2048;
    float a = 0.f, g = 0.f;
#pragma unroll
    for (int i = 0; i < 8; ++i) {
        float4 x = ((const float4*)vr)[i * 64 + lane];
        float4 wg = ((const float4*)W_gate)[i * 64 + lane];
        a += x.x * x.x + x.y * x.y + x.z * x.z + x.w * x.w;
        g += x.x * wg.x + x.y * wg.y + x.z * wg.z + x.w * wg.w;
    }
#pragma unroll
    for (int o = 32; o > 0; o >>= 1) { a += __shfl_down(a, o); g += __shfl_down(g, o); }
    if (lane == 0) {
        n2[bs] = a;
        atomicAdd(&g_logit[bs >> 6], g);
    }
}

// p2[p] = |proto[p]|^2. grid 20 x 64.
__global__ __launch_bounds__(64) void k_p2(const float* __restrict__ proto,
                                           float* __restrict__ p2)
{
    const int lane = threadIdx.x;
    const float* pr = proto + (size_t)blockIdx.x * 2048;
    float a = 0.f;
#pragma unroll
    for (int i = 0; i < 8; ++i) {
        float4 x = ((const float4*)pr)[i * 64 + lane];
        a += x.x * x.x + x.y * x.y + x.z * x.z + x.w * x.w;
    }
#pragma unroll
    for (int o = 32; o > 0; o >>= 1) a += __shfl_down(a, o);
    if (lane == 0) p2[blockIdx.x] = a;
}

// dd_logit[b] = sum_{s,p} log((d+1)/(d+1e-8)) * W_dd[s*20+p]. grid 64.
__global__ __launch_bounds__(256) void k_dd(const float* __restrict__ dots,
                                            const float* __restrict__ n2,
                                            const float* __restrict__ p2,
                                            const float* __restrict__ W_dd,
                                            float* __restrict__ dd_logit)
{
    __shared__ float red[4];
    const int b = blockIdx.x;
    const int tid = threadIdx.x, lane = tid & 63, w = tid >> 6;
    float acc = 0.f;
    for (int u = tid; u < 1280; u += 256) {
        int s = u / 20, p = u - s * 20;
        int bs = b * 64 + s;
        float d = n2[bs] - 2.f * dots[(size_t)bs * 32 + p] + p2[p];
        acc += logf((d + 1.0f) / (d + 1e-8f)) * W_dd[s * 20 + p];
    }
#pragma unroll
    for (int o = 32; o > 0; o >>= 1) acc += __shfl_down(acc, o);
    if (lane == 0) red[w] = acc;
    __syncthreads();
    if (tid == 0) dd_logit[b] = red[0] + red[1] + red[2] + red[3];
}

// ---------------------------------------------------------------------------
// Persistent LSTM: 64 blocks x 256 threads. Block bn owns n' in [bn*32, +32)
// (j = bn*8..bn*8+8, gates packed n'=j*4+g). Operand-swapped MFMA: A=Wh rows
// (from LDS), B=h^T -> D reg index IS the gate. Distributed-flag barrier:
// one flag per (step, wave), each thread polls exactly one flag.
// ---------------------------------------------------------------------------
__global__ __launch_bounds__(256) void k_lstm_persist(
    const ushort* __restrict__ xg,       // [s][b][n'] bf16
    const ushort* __restrict__ Whr,      // [n'=2048][k=512] bf16
    ushort* __restrict__ h0,             // [b][j] bf16 ping (pre-zeroed)
    ushort* __restrict__ h1,             // pong (pre-zeroed)
    int* __restrict__ flags,             // [64][256] pre-zeroed
    const float* __restrict__ W_dec, const float* __restrict__ b_dec,
    const float* __restrict__ dd_logit, const float* __restrict__ b_dd,
    const float* __restrict__ g_logit, const float* __restrict__ b_gate,
    float* __restrict__ out)
{
    __shared__ ushort Bs[32][520];       // 33.3 KB weight slice
    const int tid = threadIdx.x;
    const int lane = tid & 63, w = tid >> 6;
    const int quad = lane >> 4, l16 = lane & 15;
    const int bn = blockIdx.x;
    const int n0 = bn * 32;

    for (int c = tid; c < 2048; c += 256) {
        int row = c >> 6, chunk = c & 63;
        *(uint4*)&Bs[row][chunk * 8] = *(const uint4*)(Whr + (size_t)(n0 + row) * 512 + chunk * 8);
    }
    __syncthreads();

    const int b_glob = w * 16 + l16;     // this lane's batch row
    float c0r = 0.f, c1r = 0.f;          // c for (b_glob, j=bn*8+quad), (b_glob, j=bn*8+4+quad)

    for (int s = 0; s < 64; ++s) {
        // prefetch xg for this step (independent of barrier; in flight during spin)
        const ushort* xrow = xg + ((size_t)(s * 64 + b_glob)) * 2048 + n0;
        ushort4 xa = *(const ushort4*)(xrow + quad * 4);
        ushort4 xb = *(const ushort4*)(xrow + 16 + quad * 4);

        if (s > 0) {
            const int* f = flags + (s - 1) * 256 + tid;
            while (__hip_atomic_load(f, __ATOMIC_ACQUIRE, __HIP_MEMORY_SCOPE_AGENT) == 0) {}
            __syncthreads();
        }
        const ushort* hin = (s & 1) ? h1 : h0;
        ushort* hout = (s & 1) ? h0 : h1;

        f32x4 a0a = {}, a0b = {}, a1a = {}, a1b = {};
        const ushort* arow = hin + (size_t)b_glob * 512 + quad * 8;
#pragma unroll
        for (int kk = 0; kk < 8; ++kk) {
            short8 hb0 = *(const short8*)(arow + kk * 32);
            short8 hb1 = *(const short8*)(arow + (kk + 8) * 32);
            short8 w0a = *(const short8*)&Bs[l16][kk * 32 + quad * 8];
            short8 w0b = *(const short8*)&Bs[l16][(kk + 8) * 32 + quad * 8];
            short8 w1a = *(const short8*)&Bs[16 + l16][kk * 32 + quad * 8];
            short8 w1b = *(const short8*)&Bs[16 + l16][(kk + 8) * 32 + quad * 8];
            a0a = __builtin_amdgcn_mfma_f32_16x16x32_bf16(w0a, hb0, a0a, 0, 0, 0);
            a0b = __builtin_amdgcn_mfma_f32_16x16x32_bf16(w0b, hb1, a0b, 0, 0, 0);
            a1a = __builtin_amdgcn_mfma_f32_16x16x32_bf16(w1a, hb0, a1a, 0, 0, 0);
            a1b = __builtin_amdgcn_mfma_f32_16x16x32_bf16(w1b, hb1, a1b, 0, 0, 0);
        }
        f32x4 g0 = a0a + a0b;   // n' = n0 + quad*4 + reg  -> reg = gate
        f32x4 g1 = a1a + a1b;   // n' = n0 + 16 + quad*4 + reg
        {
            float gi = sigm(g0[0] + bf2f(xa.x));
            float gf = sigm(g0[1] + bf2f(xa.y));
            float go = sigm(g0[2] + bf2f(xa.z));
            float gg = tanh_fast(g0[3] + bf2f(xa.w));
            c0r = gf * c0r + gi * gg;
            hout[(size_t)b_glob * 512 + bn * 8 + quad] = f2bf(go * c0r);   // no tanh on c
        }
        {
            float gi = sigm(g1[0] + bf2f(xb.x));
            float gf = sigm(g1[1] + bf2f(xb.y));
            float go = sigm(g1[2] + bf2f(xb.z));
            float gg = tanh_fast(g1[3] + bf2f(xb.w));
            c1r = gf * c1r + gi * gg;
            hout[(size_t)b_glob * 512 + bn * 8 + 4 + quad] = f2bf(go * c1r);
        }
        if (lane == 0)
            __hip_atomic_store(flags + s * 256 + bn * 4 + w, 1,
                               __ATOMIC_RELEASE, __HIP_MEMORY_SCOPE_AGENT);
    }

    // final head: h(64) is in h0 (step 63 wrote h0)
    if (bn == 0) {
        const int* f = flags + 63 * 256 + tid;
        while (__hip_atomic_load(f, __ATOMIC_ACQUIRE, __HIP_MEMORY_SCOPE_AGENT) == 0) {}
        __syncthreads();
        if (w == 0) {
            int b = lane;
            const ushort* hrow = h0 + (size_t)b * 512;
            float acc = 0.f;
            for (int jj = 0; jj < 512; ++jj) acc += bf2f(hrow[jj]) * W_dec[jj];
            float output = sigm(acc + b_dec[0]);
            float gate   = sigm(g_logit[b] * (1.0f / 64.f) + b_gate[0]);
            float ddp    = sigm(dd_logit[b] + b_dd[0]);
            out[b] = output * gate + ddp * (1.f - gate);
        }
    }
}

extern "C" void kernel_launch(void* const* d_in, const int* in_sizes, int n_in,
                              void* d_out, int out_size, void* d_ws, size_t ws_size,
                              hipStream_t stream) {
    const float* v_feat   = (const float*)d_in[0];
    const int*   category = (const int*)d_in[1];
    const float* W_enc    = (const float*)d_in[2];
    const float* b_enc    = (const float*)d_in[3];
    const float* Wx       = (const float*)d_in[4];
    const float* bx       = (const float*)d_in[5];
    const float* Wh       = (const float*)d_in[6];
    const float* bh       = (const float*)d_in[7];
    const float* cat_emb  = (const float*)d_in[8];
    const float* W_dec    = (const float*)d_in[9];
    const float* b_dec    = (const float*)d_in[10];
    const float* proto    = (const float*)d_in[11];
    const float* W_dd     = (const float*)d_in[12];
    const float* b_dd     = (const float*)d_in[13];
    const float* W_gate   = (const float*)d_in[14];
    const float* b_gate   = (const float*)d_in[15];
    float* out = (float*)d_out;

    char* ws = (char*)d_ws;
    ushort* xg       = (ushort*)(ws + 0);          // 16 MB bf16 [s][b][n']
    ushort* v_bf16   = (ushort*)(ws + 0);          // 16 MB (dead before GEMM2 writes xg)
    ushort* fuse     = (ushort*)(ws + 16777216);   // 4 MB bf16 [4096][512]
    ushort* Whr      = (ushort*)(ws + 20971520);   // 2 MB bf16 [2048][512] (n' rows)
    ushort* Wenc_t   = (ushort*)(ws + 23068672);   // 2 MB bf16 [512][2048]
    ushort* Wx_t     = (ushort*)(ws + 25165824);   // 2 MB bf16 [2048][512] (n' rows)
    ushort* proto_bf = (ushort*)(ws + 27262976);   // 128 KB [32][2048]
    float*  dots     = (float*)(ws + 27394048);    // 512 KB [4096][32]
    float*  n2       = (float*)(ws + 27918336);    // 16 KB
    float*  p2       = (float*)(ws + 27934720);    // 512 B
    float*  bxh      = (float*)(ws + 27935232);    // 8 KB
    ushort* h0       = (ushort*)(ws + 27943424);   // 64 KB
    ushort* h1       = (ushort*)(ws + 28008960);   // 64 KB
    int*    flags    = (int*)(ws + 28074496);      // 64 KB [64][256]
    float*  dd_logit = (float*)(ws + 28140032);    // 256 B
    float*  g_logit  = (float*)(ws + 28140288);    // 256 B

    hipMemsetAsync(proto_bf, 0, 131072, stream);
    hipMemsetAsync(h0, 0, 197120, stream);   // h0,h1,flags,dd_logit,g_logit (contiguous)

    k_f32_to_bf16<<<8192, 256, 0, stream>>>(v_feat, v_bf16);
    k_f32_to_bf16<<<40, 256, 0, stream>>>(proto, proto_bf);
    k_bias<<<8, 256, 0, stream>>>(bx, bh, bxh);
    k_transpose_bf16<<<dim3(16, 64), 256, 0, stream>>>(W_enc, Wenc_t, 2048, 512, 0);
    k_transpose_bf16<<<dim3(64, 16), 256, 0, stream>>>(Wx, Wx_t, 512, 2048, 1);
    k_transpose_bf16<<<dim3(64, 16), 256, 0, stream>>>(Wh, Whr, 512, 2048, 1);

    k_gemm_mfma<<<dim3(4, 32), 256, 0, stream>>>(v_bf16, Wenc_t, 4096, 512, 2048,
                                                 b_enc, cat_emb, category, fuse, 0);
    k_dot<<<64, 256, 0, stream>>>(v_bf16, proto_bf, dots);
    k_rowstats<<<1024, 256, 0, stream>>>(v_feat, W_gate, n2, g_logit);
    k_p2<<<20, 64, 0, stream>>>(proto, p2);
    k_dd<<<64, 256, 0, stream>>>(dots, n2, p2, W_dd, dd_logit);

    k_gemm_mfma<<<dim3(16, 32), 256, 0, stream>>>(fuse, Wx_t, 4096, 2048, 512,
                                                  bxh, nullptr, nullptr, xg, 1);

    k_lstm_persist<<<64, 256, 0, stream>>>(xg, Whr, h0, h1, flags,
                                           W_dec, b_dec, dd_logit, b_dd,
                                           g_logit, b_gate, out);
}

// Round 5
// 715.762 us; speedup vs baseline: 1.6373x; 1.6373x over previous
//
#include <hip/hip_runtime.h>
#include <cstdint>
#include <cstddef>

// ---------------------------------------------------------------------------
// ASD_RNN round 5: persistent LSTM with relaxed-poll / single-fence barrier
// (monotonic per-block flags). Rest identical to round 4.
// B=64, S=64, F_IN=2048, H=512, 4H=2048, P2=20.
// ---------------------------------------------------------------------------

typedef __attribute__((ext_vector_type(8))) short short8;
typedef __attribute__((ext_vector_type(4))) float f32x4;

__device__ __forceinline__ ushort f2bf(float x) {
    uint32_t u = __float_as_uint(x);
    return (ushort)((u + 0x7FFF + ((u >> 16) & 1)) >> 16);   // RNE
}
__device__ __forceinline__ float bf2f(ushort u) {
    return __uint_as_float(((uint32_t)u) << 16);
}
__device__ __forceinline__ float sigm(float x) { return 1.f / (1.f + expf(-x)); }
__device__ __forceinline__ float tanh_fast(float x) { return 2.f / (1.f + expf(-2.f * x)) - 1.f; }

// fp32 -> bf16 elementwise (4 elems/thread)
__global__ __launch_bounds__(256) void k_f32_to_bf16(const float* __restrict__ in,
                                                     ushort* __restrict__ out) {
    int i = blockIdx.x * 256 + threadIdx.x;
    float4 v = ((const float4*)in)[i];
    ushort4 o;
    o.x = f2bf(v.x); o.y = f2bf(v.y); o.z = f2bf(v.z); o.w = f2bf(v.w);
    ((ushort4*)out)[i] = o;
}

// bxh[n'] = bx[n] + bh[n], n' = (n&511)*4 | (n>>9). grid 8 x 256.
__global__ __launch_bounds__(256) void k_bias(const float* __restrict__ bx,
                                              const float* __restrict__ bh,
                                              float* __restrict__ bxh) {
    int n = blockIdx.x * 256 + threadIdx.x;
    int np = ((n & 511) << 2) | (n >> 9);
    bxh[np] = bx[n] + bh[n];
}

// in [R][C] fp32 -> out [C][R] bf16, 32x32 LDS tiles. grid (C/32, R/32)
// remap!=0: output row n remapped to ((n&511)<<2)|(n>>9)  (j*4+gate order)
__global__ __launch_bounds__(256) void k_transpose_bf16(const float* __restrict__ in,
                                                        ushort* __restrict__ out,
                                                        int R, int C, int remap) {
    __shared__ float t[32][33];
    int r0 = blockIdx.y * 32, c0 = blockIdx.x * 32;
    int rr = threadIdx.x >> 3, cc = (threadIdx.x & 7) * 4;
    float4 v = *(const float4*)(in + (size_t)(r0 + rr) * C + c0 + cc);
    t[rr][cc + 0] = v.x; t[rr][cc + 1] = v.y; t[rr][cc + 2] = v.z; t[rr][cc + 3] = v.w;
    __syncthreads();
    ushort4 o;
    o.x = f2bf(t[cc + 0][rr]);
    o.y = f2bf(t[cc + 1][rr]);
    o.z = f2bf(t[cc + 2][rr]);
    o.w = f2bf(t[cc + 3][rr]);
    int n = c0 + rr;
    int np = remap ? (((n & 511) << 2) | (n >> 9)) : n;
    *(ushort4*)(out + (size_t)np * R + r0 + cc) = o;
}

// bf16 MFMA GEMM: C[M,N] = A[M,K] @ Bt[N,K]^T. 128x128 tile, 4 waves of 64x64.
// mode 0: fuse (bf16 [M][512]) = relu(acc+bias0[n]) + cat_emb[category[m>>6]][n]
// mode 1: xg (bf16 [s][b][n]) = acc + bias0[n]; m=b*64+s (n axis pre-remapped to n')
__global__ __launch_bounds__(256) void k_gemm_mfma(
    const ushort* __restrict__ A, const ushort* __restrict__ Bt,
    int M, int N, int K,
    const float* __restrict__ bias0,
    const float* __restrict__ cat_emb, const int* __restrict__ category,
    void* __restrict__ Cout, int mode)
{
    __shared__ ushort As[128][40];
    __shared__ ushort Bs[128][40];
    const int tid = threadIdx.x;
    const int lane = tid & 63, w = tid >> 6;
    const int quad = lane >> 4, l16 = lane & 15;
    const int m0 = blockIdx.y * 128, n0 = blockIdx.x * 128;
    const int wm = (w & 1) * 64, wn = (w >> 1) * 64;

    f32x4 acc[4][4] = {};
    const int lr = tid >> 2;
    const int lc = (tid & 3) * 8;

    for (int k0 = 0; k0 < K; k0 += 32) {
        uint4 a0 = *(const uint4*)(A + (size_t)(m0 + lr) * K + k0 + lc);
        uint4 a1 = *(const uint4*)(A + (size_t)(m0 + 64 + lr) * K + k0 + lc);
        uint4 b0 = *(const uint4*)(Bt + (size_t)(n0 + lr) * K + k0 + lc);
        uint4 b1 = *(const uint4*)(Bt + (size_t)(n0 + 64 + lr) * K + k0 + lc);
        __syncthreads();
        *(uint4*)&As[lr][lc] = a0;
        *(uint4*)&As[64 + lr][lc] = a1;
        *(uint4*)&Bs[lr][lc] = b0;
        *(uint4*)&Bs[64 + lr][lc] = b1;
        __syncthreads();
        short8 af[4], bf[4];
#pragma unroll
        for (int i = 0; i < 4; ++i) af[i] = *(const short8*)&As[wm + i * 16 + l16][quad * 8];
#pragma unroll
        for (int j = 0; j < 4; ++j) bf[j] = *(const short8*)&Bs[wn + j * 16 + l16][quad * 8];
#pragma unroll
        for (int i = 0; i < 4; ++i)
#pragma unroll
            for (int j = 0; j < 4; ++j)
                acc[i][j] = __builtin_amdgcn_mfma_f32_16x16x32_bf16(af[i], bf[j], acc[i][j], 0, 0, 0);
    }

    if (mode == 0) {
        ushort* C = (ushort*)Cout;
#pragma unroll
        for (int i = 0; i < 4; ++i) {
            int mbase = m0 + wm + i * 16 + quad * 4;
#pragma unroll
            for (int r = 0; r < 4; ++r) {
                int m = mbase + r;
                const float* ce = cat_emb + category[m >> 6] * 512;
#pragma unroll
                for (int j = 0; j < 4; ++j) {
                    int n = n0 + wn + j * 16 + l16;
                    float v = fmaxf(acc[i][j][r] + bias0[n], 0.f) + ce[n];
                    C[(size_t)m * 512 + n] = f2bf(v);
                }
            }
        }
    } else {
        ushort* C = (ushort*)Cout;
        float bb[4];
#pragma unroll
        for (int j = 0; j < 4; ++j) bb[j] = bias0[n0 + wn + j * 16 + l16];
#pragma unroll
        for (int i = 0; i < 4; ++i) {
            int mbase = m0 + wm + i * 16 + quad * 4;
#pragma unroll
            for (int r = 0; r < 4; ++r) {
                int m = mbase + r;
                int s = m & 63, b = m >> 6;
                ushort* crow = C + ((size_t)(s * 64 + b)) * 2048;
#pragma unroll
                for (int j = 0; j < 4; ++j)
                    crow[n0 + wn + j * 16 + l16] = f2bf(acc[i][j][r] + bb[j]);
            }
        }
    }
}

// dots[bs][p] = v_bf16[bs][:] . proto_bf[p][:] (proto padded to 32 rows)
__global__ __launch_bounds__(256) void k_dot(const ushort* __restrict__ v_bf,
                                             const ushort* __restrict__ proto_bf,
                                             float* __restrict__ dots)
{
    const int tid = threadIdx.x;
    const int lane = tid & 63, w = tid >> 6;
    const int quad = lane >> 4, l16 = lane & 15;
    const int r0 = blockIdx.x * 64 + w * 16;

    f32x4 acc[2] = {};
    const ushort* arow = v_bf + (size_t)(r0 + l16) * 2048 + quad * 8;
    const ushort* b0p = proto_bf + (size_t)l16 * 2048 + quad * 8;
    const ushort* b1p = proto_bf + (size_t)(16 + l16) * 2048 + quad * 8;
#pragma unroll 8
    for (int kk = 0; kk < 64; ++kk) {
        short8 af = *(const short8*)(arow + kk * 32);
        short8 bf0 = *(const short8*)(b0p + kk * 32);
        short8 bf1 = *(const short8*)(b1p + kk * 32);
        acc[0] = __builtin_amdgcn_mfma_f32_16x16x32_bf16(af, bf0, acc[0], 0, 0, 0);
        acc[1] = __builtin_amdgcn_mfma_f32_16x16x32_bf16(af, bf1, acc[1], 0, 0, 0);
    }
#pragma unroll
    for (int t = 0; t < 2; ++t)
#pragma unroll
        for (int r = 0; r < 4; ++r)
            dots[(size_t)(r0 + quad * 4 + r) * 32 + t * 16 + l16] = acc[t][r];
}

// per-row |v|^2 and gate-logit partials. grid 1024 blocks x 4 rows.
__global__ __launch_bounds__(256) void k_rowstats(const float* __restrict__ v_feat,
                                                  const float* __restrict__ W_gate,
                                                  float* __restrict__ n2,
                                                  float* __restrict__ g_logit)
{
    const int lane = threadIdx.x & 63, w = threadIdx.x >> 6;
    const int bs = blockIdx.x * 4 + w;
    const float* vr = v_feat + (size_t)bs * 2048;
    float a = 0.f, g = 0.f;
#pragma unroll
    for (int i = 0; i < 8; ++i) {
        float4 x = ((const float4*)vr)[i * 64 + lane];
        float4 wg = ((const float4*)W_gate)[i * 64 + lane];
        a += x.x * x.x + x.y * x.y + x.z * x.z + x.w * x.w;
        g += x.x * wg.x + x.y * wg.y + x.z * wg.z + x.w * wg.w;
    }
#pragma unroll
    for (int o = 32; o > 0; o >>= 1) { a += __shfl_down(a, o); g += __shfl_down(g, o); }
    if (lane == 0) {
        n2[bs] = a;
        atomicAdd(&g_logit[bs >> 6], g);
    }
}

// p2[p] = |proto[p]|^2. grid 20 x 64.
__global__ __launch_bounds__(64) void k_p2(const float* __restrict__ proto,
                                           float* __restrict__ p2)
{
    const int lane = threadIdx.x;
    const float* pr = proto + (size_t)blockIdx.x * 2048;
    float a = 0.f;
#pragma unroll
    for (int i = 0; i < 8; ++i) {
        float4 x = ((const float4*)pr)[i * 64 + lane];
        a += x.x * x.x + x.y * x.y + x.z * x.z + x.w * x.w;
    }
#pragma unroll
    for (int o = 32; o > 0; o >>= 1) a += __shfl_down(a, o);
    if (lane == 0) p2[blockIdx.x] = a;
}

// dd_logit[b] = sum_{s,p} log((d+1)/(d+1e-8)) * W_dd[s*20+p]. grid 64.
__global__ __launch_bounds__(256) void k_dd(const float* __restrict__ dots,
                                            const float* __restrict__ n2,
                                            const float* __restrict__ p2,
                                            const float* __restrict__ W_dd,
                                            float* __restrict__ dd_logit)
{
    __shared__ float red[4];
    const int b = blockIdx.x;
    const int tid = threadIdx.x, lane = tid & 63, w = tid >> 6;
    float acc = 0.f;
    for (int u = tid; u < 1280; u += 256) {
        int s = u / 20, p = u - s * 20;
        int bs = b * 64 + s;
        float d = n2[bs] - 2.f * dots[(size_t)bs * 32 + p] + p2[p];
        acc += logf((d + 1.0f) / (d + 1e-8f)) * W_dd[s * 20 + p];
    }
#pragma unroll
    for (int o = 32; o > 0; o >>= 1) acc += __shfl_down(acc, o);
    if (lane == 0) red[w] = acc;
    __syncthreads();
    if (tid == 0) dd_logit[b] = red[0] + red[1] + red[2] + red[3];
}

// ---------------------------------------------------------------------------
// Persistent LSTM: 64 blocks x 256 threads. Block bn owns n' in [bn*32, +32).
// Barrier: flags[bn] = monotonic step counter. Arrival = syncthreads (drains
// all waves' stores to L2) -> tid0: ONE release fence (wbl2) + relaxed store.
// Wait = wave0 lane i polls flags[i] with RELAXED agent loads (LLC, no inv)
// + s_sleep backoff, then ONE acquire fence (inv) + syncthreads.
// ---------------------------------------------------------------------------
__global__ __launch_bounds__(256) void k_lstm_persist(
    const ushort* __restrict__ xg,       // [s][b][n'] bf16
    const ushort* __restrict__ Whr,      // [n'=2048][k=512] bf16
    ushort* __restrict__ h0,             // [b][j] bf16 ping (pre-zeroed)
    ushort* __restrict__ h1,             // pong (pre-zeroed)
    int* __restrict__ flags,             // [64] pre-zeroed, monotonic
    const float* __restrict__ W_dec, const float* __restrict__ b_dec,
    const float* __restrict__ dd_logit, const float* __restrict__ b_dd,
    const float* __restrict__ g_logit, const float* __restrict__ b_gate,
    float* __restrict__ out)
{
    __shared__ ushort Bs[32][520];       // 33.3 KB weight slice
    const int tid = threadIdx.x;
    const int lane = tid & 63, w = tid >> 6;
    const int quad = lane >> 4, l16 = lane & 15;
    const int bn = blockIdx.x;
    const int n0 = bn * 32;

    for (int c = tid; c < 2048; c += 256) {
        int row = c >> 6, chunk = c & 63;
        *(uint4*)&Bs[row][chunk * 8] = *(const uint4*)(Whr + (size_t)(n0 + row) * 512 + chunk * 8);
    }
    __syncthreads();

    const int b_glob = w * 16 + l16;     // this lane's batch row
    float c0r = 0.f, c1r = 0.f;

    for (int s = 0; s < 64; ++s) {
        // prefetch xg for this step (in flight during the spin)
        const ushort* xrow = xg + ((size_t)(s * 64 + b_glob)) * 2048 + n0;
        ushort4 xa = *(const ushort4*)(xrow + quad * 4);
        ushort4 xb = *(const ushort4*)(xrow + 16 + quad * 4);

        if (s > 0) {
            if (tid < 64) {   // wave 0 only: lane i watches block i
                while (__hip_atomic_load(&flags[tid], __ATOMIC_RELAXED,
                                         __HIP_MEMORY_SCOPE_AGENT) < s)
                    __builtin_amdgcn_s_sleep(1);
                __builtin_amdgcn_fence(__ATOMIC_ACQUIRE, "agent");
            }
            __syncthreads();
        }
        const ushort* hin = (s & 1) ? h1 : h0;
        ushort* hout = (s & 1) ? h0 : h1;

        f32x4 a0a = {}, a0b = {}, a1a = {}, a1b = {};
        const ushort* arow = hin + (size_t)b_glob * 512 + quad * 8;
#pragma unroll
        for (int kk = 0; kk < 8; ++kk) {
            short8 hb0 = *(const short8*)(arow + kk * 32);
            short8 hb1 = *(const short8*)(arow + (kk + 8) * 32);
            short8 w0a = *(const short8*)&Bs[l16][kk * 32 + quad * 8];
            short8 w0b = *(const short8*)&Bs[l16][(kk + 8) * 32 + quad * 8];
            short8 w1a = *(const short8*)&Bs[16 + l16][kk * 32 + quad * 8];
            short8 w1b = *(const short8*)&Bs[16 + l16][(kk + 8) * 32 + quad * 8];
            a0a = __builtin_amdgcn_mfma_f32_16x16x32_bf16(w0a, hb0, a0a, 0, 0, 0);
            a0b = __builtin_amdgcn_mfma_f32_16x16x32_bf16(w0b, hb1, a0b, 0, 0, 0);
            a1a = __builtin_amdgcn_mfma_f32_16x16x32_bf16(w1a, hb0, a1a, 0, 0, 0);
            a1b = __builtin_amdgcn_mfma_f32_16x16x32_bf16(w1b, hb1, a1b, 0, 0, 0);
        }
        f32x4 g0 = a0a + a0b;   // n' = n0 + quad*4 + reg  -> reg = gate
        f32x4 g1 = a1a + a1b;   // n' = n0 + 16 + quad*4 + reg
        {
            float gi = sigm(g0[0] + bf2f(xa.x));
            float gf = sigm(g0[1] + bf2f(xa.y));
            float go = sigm(g0[2] + bf2f(xa.z));
            float gg = tanh_fast(g0[3] + bf2f(xa.w));
            c0r = gf * c0r + gi * gg;
            hout[(size_t)b_glob * 512 + bn * 8 + quad] = f2bf(go * c0r);   // no tanh on c
        }
        {
            float gi = sigm(g1[0] + bf2f(xb.x));
            float gf = sigm(g1[1] + bf2f(xb.y));
            float go = sigm(g1[2] + bf2f(xb.z));
            float gg = tanh_fast(g1[3] + bf2f(xb.w));
            c1r = gf * c1r + gi * gg;
            hout[(size_t)b_glob * 512 + bn * 8 + 4 + quad] = f2bf(go * c1r);
        }
        __syncthreads();        // drains every wave's h stores to L2
        if (tid == 0) {
            __builtin_amdgcn_fence(__ATOMIC_RELEASE, "agent");   // one wbl2
            __hip_atomic_store(&flags[bn], s + 1, __ATOMIC_RELAXED,
                               __HIP_MEMORY_SCOPE_AGENT);
        }
    }

    // final head: h(64) is in h0 (step 63 wrote h0)
    if (bn == 0) {
        if (tid < 64) {
            while (__hip_atomic_load(&flags[tid], __ATOMIC_RELAXED,
                                     __HIP_MEMORY_SCOPE_AGENT) < 64)
                __builtin_amdgcn_s_sleep(1);
            __builtin_amdgcn_fence(__ATOMIC_ACQUIRE, "agent");
        }
        __syncthreads();
        if (w == 0) {
            int b = lane;
            const ushort* hrow = h0 + (size_t)b * 512;
            float acc = 0.f;
            for (int jj = 0; jj < 512; ++jj) acc += bf2f(hrow[jj]) * W_dec[jj];
            float output = sigm(acc + b_dec[0]);
            float gate   = sigm(g_logit[b] * (1.0f / 64.f) + b_gate[0]);
            float ddp    = sigm(dd_logit[b] + b_dd[0]);
            out[b] = output * gate + ddp * (1.f - gate);
        }
    }
}

extern "C" void kernel_launch(void* const* d_in, const int* in_sizes, int n_in,
                              void* d_out, int out_size, void* d_ws, size_t ws_size,
                              hipStream_t stream) {
    const float* v_feat   = (const float*)d_in[0];
    const int*   category = (const int*)d_in[1];
    const float* W_enc    = (const float*)d_in[2];
    const float* b_enc    = (const float*)d_in[3];
    const float* Wx       = (const float*)d_in[4];
    const float* bx       = (const float*)d_in[5];
    const float* Wh       = (const float*)d_in[6];
    const float* bh       = (const float*)d_in[7];
    const float* cat_emb  = (const float*)d_in[8];
    const float* W_dec    = (const float*)d_in[9];
    const float* b_dec    = (const float*)d_in[10];
    const float* proto    = (const float*)d_in[11];
    const float* W_dd     = (const float*)d_in[12];
    const float* b_dd     = (const float*)d_in[13];
    const float* W_gate   = (const float*)d_in[14];
    const float* b_gate   = (const float*)d_in[15];
    float* out = (float*)d_out;

    char* ws = (char*)d_ws;
    ushort* xg       = (ushort*)(ws + 0);          // 16 MB bf16 [s][b][n']
    ushort* v_bf16   = (ushort*)(ws + 0);          // 16 MB (dead before GEMM2 writes xg)
    ushort* fuse     = (ushort*)(ws + 16777216);   // 4 MB bf16 [4096][512]
    ushort* Whr      = (ushort*)(ws + 20971520);   // 2 MB bf16 [2048][512] (n' rows)
    ushort* Wenc_t   = (ushort*)(ws + 23068672);   // 2 MB bf16 [512][2048]
    ushort* Wx_t     = (ushort*)(ws + 25165824);   // 2 MB bf16 [2048][512] (n' rows)
    ushort* proto_bf = (ushort*)(ws + 27262976);   // 128 KB [32][2048]
    float*  dots     = (float*)(ws + 27394048);    // 512 KB [4096][32]
    float*  n2       = (float*)(ws + 27918336);    // 16 KB
    float*  p2       = (float*)(ws + 27934720);    // 512 B
    float*  bxh      = (float*)(ws + 27935232);    // 8 KB
    ushort* h0       = (ushort*)(ws + 27943424);   // 64 KB
    ushort* h1       = (ushort*)(ws + 28008960);   // 64 KB
    int*    flags    = (int*)(ws + 28074496);      // 64 KB region, 64 words used
    float*  dd_logit = (float*)(ws + 28140032);    // 256 B
    float*  g_logit  = (float*)(ws + 28140288);    // 256 B

    hipMemsetAsync(proto_bf, 0, 131072, stream);
    hipMemsetAsync(h0, 0, 197120, stream);   // h0,h1,flags,dd_logit,g_logit (contiguous)

    k_f32_to_bf16<<<8192, 256, 0, stream>>>(v_feat, v_bf16);
    k_f32_to_bf16<<<40, 256, 0, stream>>>(proto, proto_bf);
    k_bias<<<8, 256, 0, stream>>>(bx, bh, bxh);
    k_transpose_bf16<<<dim3(16, 64), 256, 0, stream>>>(W_enc, Wenc_t, 2048, 512, 0);
    k_transpose_bf16<<<dim3(64, 16), 256, 0, stream>>>(Wx, Wx_t, 512, 2048, 1);
    k_transpose_bf16<<<dim3(64, 16), 256, 0, stream>>>(Wh, Whr, 512, 2048, 1);

    k_gemm_mfma<<<dim3(4, 32), 256, 0, stream>>>(v_bf16, Wenc_t, 4096, 512, 2048,
                                                 b_enc, cat_emb, category, fuse, 0);
    k_dot<<<64, 256, 0, stream>>>(v_bf16, proto_bf, dots);
    k_rowstats<<<1024, 256, 0, stream>>>(v_feat, W_gate, n2, g_logit);
    k_p2<<<20, 64, 0, stream>>>(proto, p2);
    k_dd<<<64, 256, 0, stream>>>(dots, n2, p2, W_dd, dd_logit);

    k_gemm_mfma<<<dim3(16, 32), 256, 0, stream>>>(fuse, Wx_t, 4096, 2048, 512,
                                                  bxh, nullptr, nullptr, xg, 1);

    k_lstm_persist<<<64, 256, 0, stream>>>(xg, Whr, h0, h1, flags,
                                           W_dec, b_dec, dd_logit, b_dd,
                                           g_logit, b_gate, out);
}

// Round 6
// 636.181 us; speedup vs baseline: 1.8421x; 1.1251x over previous
//
#include <hip/hip_runtime.h>
#include <cstdint>
#include <cstddef>

// ---------------------------------------------------------------------------
// ASD_RNN round 6: fence-free persistent LSTM — h exchange via LLC-direct
// (sc1) relaxed agent atomics, fragment-linear LDS weights (0 conflicts).
// B=64, S=64, F_IN=2048, H=512, 4H=2048, P2=20.
// ---------------------------------------------------------------------------

typedef __attribute__((ext_vector_type(8))) short short8;
typedef __attribute__((ext_vector_type(4))) float f32x4;
typedef unsigned long long ull;

__device__ __forceinline__ ushort f2bf(float x) {
    uint32_t u = __float_as_uint(x);
    return (ushort)((u + 0x7FFF + ((u >> 16) & 1)) >> 16);   // RNE
}
__device__ __forceinline__ float bf2f(ushort u) {
    return __uint_as_float(((uint32_t)u) << 16);
}
__device__ __forceinline__ float sigm(float x) { return 1.f / (1.f + expf(-x)); }
__device__ __forceinline__ float tanh_fast(float x) { return 2.f / (1.f + expf(-2.f * x)) - 1.f; }

// 16B of h via two 8B LLC-direct (agent-scope, sc1) relaxed loads.
__device__ __forceinline__ short8 ld_h16(const ushort* p) {
    union { ull u[2]; short8 s; } t;
    t.u[0] = __hip_atomic_load((const ull*)p, __ATOMIC_RELAXED, __HIP_MEMORY_SCOPE_AGENT);
    t.u[1] = __hip_atomic_load((const ull*)(p + 4), __ATOMIC_RELAXED, __HIP_MEMORY_SCOPE_AGENT);
    return t.s;
}

// fp32 -> bf16 elementwise (4 elems/thread)
__global__ __launch_bounds__(256) void k_f32_to_bf16(const float* __restrict__ in,
                                                     ushort* __restrict__ out) {
    int i = blockIdx.x * 256 + threadIdx.x;
    float4 v = ((const float4*)in)[i];
    ushort4 o;
    o.x = f2bf(v.x); o.y = f2bf(v.y); o.z = f2bf(v.z); o.w = f2bf(v.w);
    ((ushort4*)out)[i] = o;
}

// bxh[n'] = bx[n] + bh[n], n' = (n&511)*4 | (n>>9). grid 8 x 256.
__global__ __launch_bounds__(256) void k_bias(const float* __restrict__ bx,
                                              const float* __restrict__ bh,
                                              float* __restrict__ bxh) {
    int n = blockIdx.x * 256 + threadIdx.x;
    int np = ((n & 511) << 2) | (n >> 9);
    bxh[np] = bx[n] + bh[n];
}

// in [R][C] fp32 -> out [C][R] bf16, 32x32 LDS tiles. grid (C/32, R/32)
// remap!=0: output row n remapped to ((n&511)<<2)|(n>>9)  (j*4+gate order)
__global__ __launch_bounds__(256) void k_transpose_bf16(const float* __restrict__ in,
                                                        ushort* __restrict__ out,
                                                        int R, int C, int remap) {
    __shared__ float t[32][33];
    int r0 = blockIdx.y * 32, c0 = blockIdx.x * 32;
    int rr = threadIdx.x >> 3, cc = (threadIdx.x & 7) * 4;
    float4 v = *(const float4*)(in + (size_t)(r0 + rr) * C + c0 + cc);
    t[rr][cc + 0] = v.x; t[rr][cc + 1] = v.y; t[rr][cc + 2] = v.z; t[rr][cc + 3] = v.w;
    __syncthreads();
    ushort4 o;
    o.x = f2bf(t[cc + 0][rr]);
    o.y = f2bf(t[cc + 1][rr]);
    o.z = f2bf(t[cc + 2][rr]);
    o.w = f2bf(t[cc + 3][rr]);
    int n = c0 + rr;
    int np = remap ? (((n & 511) << 2) | (n >> 9)) : n;
    *(ushort4*)(out + (size_t)np * R + r0 + cc) = o;
}

// bf16 MFMA GEMM: C[M,N] = A[M,K] @ Bt[N,K]^T. 128x128 tile, 4 waves of 64x64.
// mode 0: fuse (bf16 [M][512]) = relu(acc+bias0[n]) + cat_emb[category[m>>6]][n]
// mode 1: xg (bf16 [s][b][n]) = acc + bias0[n]; m=b*64+s (n axis pre-remapped to n')
__global__ __launch_bounds__(256) void k_gemm_mfma(
    const ushort* __restrict__ A, const ushort* __restrict__ Bt,
    int M, int N, int K,
    const float* __restrict__ bias0,
    const float* __restrict__ cat_emb, const int* __restrict__ category,
    void* __restrict__ Cout, int mode)
{
    __shared__ ushort As[128][40];
    __shared__ ushort Bs[128][40];
    const int tid = threadIdx.x;
    const int lane = tid & 63, w = tid >> 6;
    const int quad = lane >> 4, l16 = lane & 15;
    const int m0 = blockIdx.y * 128, n0 = blockIdx.x * 128;
    const int wm = (w & 1) * 64, wn = (w >> 1) * 64;

    f32x4 acc[4][4] = {};
    const int lr = tid >> 2;
    const int lc = (tid & 3) * 8;

    for (int k0 = 0; k0 < K; k0 += 32) {
        uint4 a0 = *(const uint4*)(A + (size_t)(m0 + lr) * K + k0 + lc);
        uint4 a1 = *(const uint4*)(A + (size_t)(m0 + 64 + lr) * K + k0 + lc);
        uint4 b0 = *(const uint4*)(Bt + (size_t)(n0 + lr) * K + k0 + lc);
        uint4 b1 = *(const uint4*)(Bt + (size_t)(n0 + 64 + lr) * K + k0 + lc);
        __syncthreads();
        *(uint4*)&As[lr][lc] = a0;
        *(uint4*)&As[64 + lr][lc] = a1;
        *(uint4*)&Bs[lr][lc] = b0;
        *(uint4*)&Bs[64 + lr][lc] = b1;
        __syncthreads();
        short8 af[4], bf[4];
#pragma unroll
        for (int i = 0; i < 4; ++i) af[i] = *(const short8*)&As[wm + i * 16 + l16][quad * 8];
#pragma unroll
        for (int j = 0; j < 4; ++j) bf[j] = *(const short8*)&Bs[wn + j * 16 + l16][quad * 8];
#pragma unroll
        for (int i = 0; i < 4; ++i)
#pragma unroll
            for (int j = 0; j < 4; ++j)
                acc[i][j] = __builtin_amdgcn_mfma_f32_16x16x32_bf16(af[i], bf[j], acc[i][j], 0, 0, 0);
    }

    if (mode == 0) {
        ushort* C = (ushort*)Cout;
#pragma unroll
        for (int i = 0; i < 4; ++i) {
            int mbase = m0 + wm + i * 16 + quad * 4;
#pragma unroll
            for (int r = 0; r < 4; ++r) {
                int m = mbase + r;
                const float* ce = cat_emb + category[m >> 6] * 512;
#pragma unroll
                for (int j = 0; j < 4; ++j) {
                    int n = n0 + wn + j * 16 + l16;
                    float v = fmaxf(acc[i][j][r] + bias0[n], 0.f) + ce[n];
                    C[(size_t)m * 512 + n] = f2bf(v);
                }
            }
        }
    } else {
        ushort* C = (ushort*)Cout;
        float bb[4];
#pragma unroll
        for (int j = 0; j < 4; ++j) bb[j] = bias0[n0 + wn + j * 16 + l16];
#pragma unroll
        for (int i = 0; i < 4; ++i) {
            int mbase = m0 + wm + i * 16 + quad * 4;
#pragma unroll
            for (int r = 0; r < 4; ++r) {
                int m = mbase + r;
                int s = m & 63, b = m >> 6;
                ushort* crow = C + ((size_t)(s * 64 + b)) * 2048;
#pragma unroll
                for (int j = 0; j < 4; ++j)
                    crow[n0 + wn + j * 16 + l16] = f2bf(acc[i][j][r] + bb[j]);
            }
        }
    }
}

// dots[bs][p] = v_bf16[bs][:] . proto_bf[p][:] (proto padded to 32 rows)
__global__ __launch_bounds__(256) void k_dot(const ushort* __restrict__ v_bf,
                                             const ushort* __restrict__ proto_bf,
                                             float* __restrict__ dots)
{
    const int tid = threadIdx.x;
    const int lane = tid & 63, w = tid >> 6;
    const int quad = lane >> 4, l16 = lane & 15;
    const int r0 = blockIdx.x * 64 + w * 16;

    f32x4 acc[2] = {};
    const ushort* arow = v_bf + (size_t)(r0 + l16) * 2048 + quad * 8;
    const ushort* b0p = proto_bf + (size_t)l16 * 2048 + quad * 8;
    const ushort* b1p = proto_bf + (size_t)(16 + l16) * 2048 + quad * 8;
#pragma unroll 8
    for (int kk = 0; kk < 64; ++kk) {
        short8 af = *(const short8*)(arow + kk * 32);
        short8 bf0 = *(const short8*)(b0p + kk * 32);
        short8 bf1 = *(const short8*)(b1p + kk * 32);
        acc[0] = __builtin_amdgcn_mfma_f32_16x16x32_bf16(af, bf0, acc[0], 0, 0, 0);
        acc[1] = __builtin_amdgcn_mfma_f32_16x16x32_bf16(af, bf1, acc[1], 0, 0, 0);
    }
#pragma unroll
    for (int t = 0; t < 2; ++t)
#pragma unroll
        for (int r = 0; r < 4; ++r)
            dots[(size_t)(r0 + quad * 4 + r) * 32 + t * 16 + l16] = acc[t][r];
}

// per-row |v|^2 and gate-logit partials. grid 1024 blocks x 4 rows.
__global__ __launch_bounds__(256) void k_rowstats(const float* __restrict__ v_feat,
                                                  const float* __restrict__ W_gate,
                                                  float* __restrict__ n2,
                                                  float* __restrict__ g_logit)
{
    const int lane = threadIdx.x & 63, w = threadIdx.x >> 6;
    const int bs = blockIdx.x * 4 + w;
    const float* vr = v_feat + (size_t)bs * 2048;
    float a = 0.f, g = 0.f;
#pragma unroll
    for (int i = 0; i < 8; ++i) {
        float4 x = ((const float4*)vr)[i * 64 + lane];
        float4 wg = ((const float4*)W_gate)[i * 64 + lane];
        a += x.x * x.x + x.y * x.y + x.z * x.z + x.w * x.w;
        g += x.x * wg.x + x.y * wg.y + x.z * wg.z + x.w * wg.w;
    }
#pragma unroll
    for (int o = 32; o > 0; o >>= 1) { a += __shfl_down(a, o); g += __shfl_down(g, o); }
    if (lane == 0) {
        n2[bs] = a;
        atomicAdd(&g_logit[bs >> 6], g);
    }
}

// p2[p] = |proto[p]|^2. grid 20 x 64.
__global__ __launch_bounds__(64) void k_p2(const float* __restrict__ proto,
                                           float* __restrict__ p2)
{
    const int lane = threadIdx.x;
    const float* pr = proto + (size_t)blockIdx.x * 2048;
    float a = 0.f;
#pragma unroll
    for (int i = 0; i < 8; ++i) {
        float4 x = ((const float4*)pr)[i * 64 + lane];
        a += x.x * x.x + x.y * x.y + x.z * x.z + x.w * x.w;
    }
#pragma unroll
    for (int o = 32; o > 0; o >>= 1) a += __shfl_down(a, o);
    if (lane == 0) p2[blockIdx.x] = a;
}

// dd_logit[b] = sum_{s,p} log((d+1)/(d+1e-8)) * W_dd[s*20+p]. grid 64.
__global__ __launch_bounds__(256) void k_dd(const float* __restrict__ dots,
                                            const float* __restrict__ n2,
                                            const float* __restrict__ p2,
                                            const float* __restrict__ W_dd,
                                            float* __restrict__ dd_logit)
{
    __shared__ float red[4];
    const int b = blockIdx.x;
    const int tid = threadIdx.x, lane = tid & 63, w = tid >> 6;
    float acc = 0.f;
    for (int u = tid; u < 1280; u += 256) {
        int s = u / 20, p = u - s * 20;
        int bs = b * 64 + s;
        float d = n2[bs] - 2.f * dots[(size_t)bs * 32 + p] + p2[p];
        acc += logf((d + 1.0f) / (d + 1e-8f)) * W_dd[s * 20 + p];
    }
#pragma unroll
    for (int o = 32; o > 0; o >>= 1) acc += __shfl_down(acc, o);
    if (lane == 0) red[w] = acc;
    __syncthreads();
    if (tid == 0) dd_logit[b] = red[0] + red[1] + red[2] + red[3];
}

// ---------------------------------------------------------------------------
// Persistent LSTM, fence-free. Block bn owns n' in [bn*32, +32).
// h stores/loads: relaxed agent atomics (sc1 -> LLC, bypass non-coherent L2).
// Barrier: __syncthreads (drains vmcnt -> h in LLC), tid0 relaxed flag store;
// wave0 lane i polls flags[i] (relaxed, LLC), then __syncthreads releases.
// Wh in LDS in fragment-linear layout: fragment (rowblk,kk,quad) at
// ((rowblk*16+kk)*4+quad)*16 + l16 (16B units) -> conflict-free ds_read_b128.
// ---------------------------------------------------------------------------
__global__ __launch_bounds__(256) void k_lstm_persist(
    const ushort* __restrict__ xg,       // [s][b][n'] bf16
    const ushort* __restrict__ Whr,      // [n'=2048][k=512] bf16
    ushort* __restrict__ h0,             // [b][j] bf16 ping (pre-zeroed, LLC)
    ushort* __restrict__ h1,             // pong
    int* __restrict__ flags,             // [64] pre-zeroed, monotonic
    const float* __restrict__ W_dec, const float* __restrict__ b_dec,
    const float* __restrict__ dd_logit, const float* __restrict__ b_dd,
    const float* __restrict__ g_logit, const float* __restrict__ b_gate,
    float* __restrict__ out)
{
    __shared__ ushort Bs[16384];         // 32 KB, fragment-linear
    __shared__ float fred[4][64];
    const int tid = threadIdx.x;
    const int lane = tid & 63, w = tid >> 6;
    const int quad = lane >> 4, l16 = lane & 15;
    const int bn = blockIdx.x;
    const int n0 = bn * 32;

    // stage weights into fragment-linear LDS
    for (int c = tid; c < 2048; c += 256) {
        int row = c >> 6, chunk = c & 63;               // chunk = 16B unit in row
        int f = ((row >> 4) * 16 + (chunk >> 2)) * 4 + (chunk & 3);
        uint4 v = *(const uint4*)(Whr + (size_t)(n0 + row) * 512 + chunk * 8);
        *(uint4*)&Bs[(f * 16 + (row & 15)) * 8] = v;
    }
    __syncthreads();

    const int b_glob = w * 16 + l16;     // this lane's batch row
    float c0r = 0.f, c1r = 0.f;

    for (int s = 0; s < 64; ++s) {
        // xg prefetch (plain loads; xg immutable, L2-cacheable)
        const ushort* xrow = xg + ((size_t)(s * 64 + b_glob)) * 2048 + n0;
        ushort4 xa = *(const ushort4*)(xrow + quad * 4);
        ushort4 xb = *(const ushort4*)(xrow + 16 + quad * 4);

        if (s > 0) {
            if (tid < 64) {
                while (__hip_atomic_load(&flags[tid], __ATOMIC_RELAXED,
                                         __HIP_MEMORY_SCOPE_AGENT) < s) {}
            }
            __syncthreads();
        }
        const ushort* hin = (s & 1) ? h1 : h0;
        ushort* hout = (s & 1) ? h0 : h1;

        f32x4 a0a = {}, a0b = {}, a1a = {}, a1b = {};
        const ushort* arow = hin + (size_t)b_glob * 512 + quad * 8;
#pragma unroll
        for (int kk = 0; kk < 8; ++kk) {
            short8 hb0 = ld_h16(arow + kk * 32);
            short8 hb1 = ld_h16(arow + (kk + 8) * 32);
            short8 w0a = *(const short8*)&Bs[(((kk) * 4 + quad) * 16 + l16) * 8];
            short8 w0b = *(const short8*)&Bs[(((kk + 8) * 4 + quad) * 16 + l16) * 8];
            short8 w1a = *(const short8*)&Bs[(((16 + kk) * 4 + quad) * 16 + l16) * 8];
            short8 w1b = *(const short8*)&Bs[(((24 + kk) * 4 + quad) * 16 + l16) * 8];
            a0a = __builtin_amdgcn_mfma_f32_16x16x32_bf16(w0a, hb0, a0a, 0, 0, 0);
            a0b = __builtin_amdgcn_mfma_f32_16x16x32_bf16(w0b, hb1, a0b, 0, 0, 0);
            a1a = __builtin_amdgcn_mfma_f32_16x16x32_bf16(w1a, hb0, a1a, 0, 0, 0);
            a1b = __builtin_amdgcn_mfma_f32_16x16x32_bf16(w1b, hb1, a1b, 0, 0, 0);
        }
        f32x4 g0 = a0a + a0b;   // n' = n0 + quad*4 + reg  -> reg = gate
        f32x4 g1 = a1a + a1b;   // n' = n0 + 16 + quad*4 + reg
        {
            float gi = sigm(g0[0] + bf2f(xa.x));
            float gf = sigm(g0[1] + bf2f(xa.y));
            float go = sigm(g0[2] + bf2f(xa.z));
            float gg = tanh_fast(g0[3] + bf2f(xa.w));
            c0r = gf * c0r + gi * gg;
            __hip_atomic_store(&hout[(size_t)b_glob * 512 + bn * 8 + quad],
                               f2bf(go * c0r), __ATOMIC_RELAXED, __HIP_MEMORY_SCOPE_AGENT);
        }
        {
            float gi = sigm(g1[0] + bf2f(xb.x));
            float gf = sigm(g1[1] + bf2f(xb.y));
            float go = sigm(g1[2] + bf2f(xb.z));
            float gg = tanh_fast(g1[3] + bf2f(xb.w));
            c1r = gf * c1r + gi * gg;
            __hip_atomic_store(&hout[(size_t)b_glob * 512 + bn * 8 + 4 + quad],
                               f2bf(go * c1r), __ATOMIC_RELAXED, __HIP_MEMORY_SCOPE_AGENT);
        }
        __syncthreads();        // pre-barrier waitcnt drains every wave's sc1 stores to LLC
        if (tid == 0)
            __hip_atomic_store(&flags[bn], s + 1, __ATOMIC_RELAXED,
                               __HIP_MEMORY_SCOPE_AGENT);
    }

    // final head: h(64) in h0 (step 63 wrote h0); must read via LLC atomics
    if (bn == 0) {
        if (tid < 64) {
            while (__hip_atomic_load(&flags[tid], __ATOMIC_RELAXED,
                                     __HIP_MEMORY_SCOPE_AGENT) < 64) {}
        }
        __syncthreads();
        int b = tid & 63, part = tid >> 6;           // each wave does 128 j's
        const ushort* hrow = h0 + (size_t)b * 512 + part * 128;
        const float* wd = W_dec + part * 128;
        float acc = 0.f;
#pragma unroll 4
        for (int jj = 0; jj < 128; jj += 4) {
            ull u = __hip_atomic_load((const ull*)(hrow + jj),
                                      __ATOMIC_RELAXED, __HIP_MEMORY_SCOPE_AGENT);
            acc += bf2f((ushort)u) * wd[jj]
                 + bf2f((ushort)(u >> 16)) * wd[jj + 1]
                 + bf2f((ushort)(u >> 32)) * wd[jj + 2]
                 + bf2f((ushort)(u >> 48)) * wd[jj + 3];
        }
        fred[part][b] = acc;
        __syncthreads();
        if (tid < 64) {
            float a = fred[0][tid] + fred[1][tid] + fred[2][tid] + fred[3][tid];
            float output = sigm(a + b_dec[0]);
            float gate   = sigm(g_logit[tid] * (1.0f / 64.f) + b_gate[0]);
            float ddp    = sigm(dd_logit[tid] + b_dd[0]);
            out[tid] = output * gate + ddp * (1.f - gate);
        }
    }
}

extern "C" void kernel_launch(void* const* d_in, const int* in_sizes, int n_in,
                              void* d_out, int out_size, void* d_ws, size_t ws_size,
                              hipStream_t stream) {
    const float* v_feat   = (const float*)d_in[0];
    const int*   category = (const int*)d_in[1];
    const float* W_enc    = (const float*)d_in[2];
    const float* b_enc    = (const float*)d_in[3];
    const float* Wx       = (const float*)d_in[4];
    const float* bx       = (const float*)d_in[5];
    const float* Wh       = (const float*)d_in[6];
    const float* bh       = (const float*)d_in[7];
    const float* cat_emb  = (const float*)d_in[8];
    const float* W_dec    = (const float*)d_in[9];
    const float* b_dec    = (const float*)d_in[10];
    const float* proto    = (const float*)d_in[11];
    const float* W_dd     = (const float*)d_in[12];
    const float* b_dd     = (const float*)d_in[13];
    const float* W_gate   = (const float*)d_in[14];
    const float* b_gate   = (const float*)d_in[15];
    float* out = (float*)d_out;

    char* ws = (char*)d_ws;
    ushort* xg       = (ushort*)(ws + 0);          // 16 MB bf16 [s][b][n']
    ushort* v_bf16   = (ushort*)(ws + 0);          // 16 MB (dead before GEMM2 writes xg)
    ushort* fuse     = (ushort*)(ws + 16777216);   // 4 MB bf16 [4096][512]
    ushort* Whr      = (ushort*)(ws + 20971520);   // 2 MB bf16 [2048][512] (n' rows)
    ushort* Wenc_t   = (ushort*)(ws + 23068672);   // 2 MB bf16 [512][2048]
    ushort* Wx_t     = (ushort*)(ws + 25165824);   // 2 MB bf16 [2048][512] (n' rows)
    ushort* proto_bf = (ushort*)(ws + 27262976);   // 128 KB [32][2048]
    float*  dots     = (float*)(ws + 27394048);    // 512 KB [4096][32]
    float*  n2       = (float*)(ws + 27918336);    // 16 KB
    float*  p2       = (float*)(ws + 27934720);    // 512 B
    float*  bxh      = (float*)(ws + 27935232);    // 8 KB
    ushort* h0       = (ushort*)(ws + 27943424);   // 64 KB
    ushort* h1       = (ushort*)(ws + 28008960);   // 64 KB
    int*    flags    = (int*)(ws + 28074496);      // 64 KB region, 64 words used
    float*  dd_logit = (float*)(ws + 28140032);    // 256 B
    float*  g_logit  = (float*)(ws + 28140288);    // 256 B

    hipMemsetAsync(proto_bf, 0, 131072, stream);
    hipMemsetAsync(h0, 0, 197120, stream);   // h0,h1,flags,dd_logit,g_logit (contiguous)

    k_f32_to_bf16<<<8192, 256, 0, stream>>>(v_feat, v_bf16);
    k_f32_to_bf16<<<40, 256, 0, stream>>>(proto, proto_bf);
    k_bias<<<8, 256, 0, stream>>>(bx, bh, bxh);
    k_transpose_bf16<<<dim3(16, 64), 256, 0, stream>>>(W_enc, Wenc_t, 2048, 512, 0);
    k_transpose_bf16<<<dim3(64, 16), 256, 0, stream>>>(Wx, Wx_t, 512, 2048, 1);
    k_transpose_bf16<<<dim3(64, 16), 256, 0, stream>>>(Wh, Whr, 512, 2048, 1);

    k_gemm_mfma<<<dim3(4, 32), 256, 0, stream>>>(v_bf16, Wenc_t, 4096, 512, 2048,
                                                 b_enc, cat_emb, category, fuse, 0);
    k_dot<<<64, 256, 0, stream>>>(v_bf16, proto_bf, dots);
    k_rowstats<<<1024, 256, 0, stream>>>(v_feat, W_gate, n2, g_logit);
    k_p2<<<20, 64, 0, stream>>>(proto, p2);
    k_dd<<<64, 256, 0, stream>>>(dots, n2, p2, W_dd, dd_logit);

    k_gemm_mfma<<<dim3(16, 32), 256, 0, stream>>>(fuse, Wx_t, 4096, 2048, 512,
                                                  bxh, nullptr, nullptr, xg, 1);

    k_lstm_persist<<<64, 256, 0, stream>>>(xg, Whr, h0, h1, flags,
                                           W_dec, b_dec, dd_logit, b_dd,
                                           g_logit, b_gate, out);
}

// Round 7
// 500.877 us; speedup vs baseline: 2.3397x; 1.2701x over previous
//
#include <hip/hip_runtime.h>
#include <cstdint>
#include <cstddef>

// ---------------------------------------------------------------------------
// ASD_RNN round 7: persistent LSTM with rotating h buffers (plain cacheable
// consumer loads, line-ownership layout), sc1 stores + relaxed flag barrier.
// B=64, S=64, F_IN=2048, H=512, 4H=2048, P2=20.
// ---------------------------------------------------------------------------

typedef __attribute__((ext_vector_type(8))) short short8;
typedef __attribute__((ext_vector_type(4))) float f32x4;
typedef unsigned long long ull;

__device__ __forceinline__ ushort f2bf(float x) {
    uint32_t u = __float_as_uint(x);
    return (ushort)((u + 0x7FFF + ((u >> 16) & 1)) >> 16);   // RNE
}
__device__ __forceinline__ float bf2f(ushort u) {
    return __uint_as_float(((uint32_t)u) << 16);
}
__device__ __forceinline__ float sigm(float x) { return 1.f / (1.f + expf(-x)); }
__device__ __forceinline__ float tanh_fast(float x) { return 2.f / (1.f + expf(-2.f * x)) - 1.f; }

// fp32 -> bf16 elementwise (4 elems/thread)
__global__ __launch_bounds__(256) void k_f32_to_bf16(const float* __restrict__ in,
                                                     ushort* __restrict__ out) {
    int i = blockIdx.x * 256 + threadIdx.x;
    float4 v = ((const float4*)in)[i];
    ushort4 o;
    o.x = f2bf(v.x); o.y = f2bf(v.y); o.z = f2bf(v.z); o.w = f2bf(v.w);
    ((ushort4*)out)[i] = o;
}

// bxh[n'] = bx[n] + bh[n], n' = (n&511)*4 | (n>>9). grid 8 x 256.
__global__ __launch_bounds__(256) void k_bias(const float* __restrict__ bx,
                                              const float* __restrict__ bh,
                                              float* __restrict__ bxh) {
    int n = blockIdx.x * 256 + threadIdx.x;
    int np = ((n & 511) << 2) | (n >> 9);
    bxh[np] = bx[n] + bh[n];
}

// in [R][C] fp32 -> out [C][R] bf16, 32x32 LDS tiles. grid (C/32, R/32)
// remap!=0: output row n remapped to ((n&511)<<2)|(n>>9)  (j*4+gate order)
__global__ __launch_bounds__(256) void k_transpose_bf16(const float* __restrict__ in,
                                                        ushort* __restrict__ out,
                                                        int R, int C, int remap) {
    __shared__ float t[32][33];
    int r0 = blockIdx.y * 32, c0 = blockIdx.x * 32;
    int rr = threadIdx.x >> 3, cc = (threadIdx.x & 7) * 4;
    float4 v = *(const float4*)(in + (size_t)(r0 + rr) * C + c0 + cc);
    t[rr][cc + 0] = v.x; t[rr][cc + 1] = v.y; t[rr][cc + 2] = v.z; t[rr][cc + 3] = v.w;
    __syncthreads();
    ushort4 o;
    o.x = f2bf(t[cc + 0][rr]);
    o.y = f2bf(t[cc + 1][rr]);
    o.z = f2bf(t[cc + 2][rr]);
    o.w = f2bf(t[cc + 3][rr]);
    int n = c0 + rr;
    int np = remap ? (((n & 511) << 2) | (n >> 9)) : n;
    *(ushort4*)(out + (size_t)np * R + r0 + cc) = o;
}

// bf16 MFMA GEMM: C[M,N] = A[M,K] @ Bt[N,K]^T. 128x128 tile, 4 waves of 64x64.
// mode 0: fuse (bf16 [M][512]) = relu(acc+bias0[n]) + cat_emb[category[m>>6]][n]
// mode 1: xg (bf16 [s][b][n]) = acc + bias0[n]; m=b*64+s (n axis pre-remapped to n')
__global__ __launch_bounds__(256) void k_gemm_mfma(
    const ushort* __restrict__ A, const ushort* __restrict__ Bt,
    int M, int N, int K,
    const float* __restrict__ bias0,
    const float* __restrict__ cat_emb, const int* __restrict__ category,
    void* __restrict__ Cout, int mode)
{
    __shared__ ushort As[128][40];
    __shared__ ushort Bs[128][40];
    const int tid = threadIdx.x;
    const int lane = tid & 63, w = tid >> 6;
    const int quad = lane >> 4, l16 = lane & 15;
    const int m0 = blockIdx.y * 128, n0 = blockIdx.x * 128;
    const int wm = (w & 1) * 64, wn = (w >> 1) * 64;

    f32x4 acc[4][4] = {};
    const int lr = tid >> 2;
    const int lc = (tid & 3) * 8;

    for (int k0 = 0; k0 < K; k0 += 32) {
        uint4 a0 = *(const uint4*)(A + (size_t)(m0 + lr) * K + k0 + lc);
        uint4 a1 = *(const uint4*)(A + (size_t)(m0 + 64 + lr) * K + k0 + lc);
        uint4 b0 = *(const uint4*)(Bt + (size_t)(n0 + lr) * K + k0 + lc);
        uint4 b1 = *(const uint4*)(Bt + (size_t)(n0 + 64 + lr) * K + k0 + lc);
        __syncthreads();
        *(uint4*)&As[lr][lc] = a0;
        *(uint4*)&As[64 + lr][lc] = a1;
        *(uint4*)&Bs[lr][lc] = b0;
        *(uint4*)&Bs[64 + lr][lc] = b1;
        __syncthreads();
        short8 af[4], bf[4];
#pragma unroll
        for (int i = 0; i < 4; ++i) af[i] = *(const short8*)&As[wm + i * 16 + l16][quad * 8];
#pragma unroll
        for (int j = 0; j < 4; ++j) bf[j] = *(const short8*)&Bs[wn + j * 16 + l16][quad * 8];
#pragma unroll
        for (int i = 0; i < 4; ++i)
#pragma unroll
            for (int j = 0; j < 4; ++j)
                acc[i][j] = __builtin_amdgcn_mfma_f32_16x16x32_bf16(af[i], bf[j], acc[i][j], 0, 0, 0);
    }

    if (mode == 0) {
        ushort* C = (ushort*)Cout;
#pragma unroll
        for (int i = 0; i < 4; ++i) {
            int mbase = m0 + wm + i * 16 + quad * 4;
#pragma unroll
            for (int r = 0; r < 4; ++r) {
                int m = mbase + r;
                const float* ce = cat_emb + category[m >> 6] * 512;
#pragma unroll
                for (int j = 0; j < 4; ++j) {
                    int n = n0 + wn + j * 16 + l16;
                    float v = fmaxf(acc[i][j][r] + bias0[n], 0.f) + ce[n];
                    C[(size_t)m * 512 + n] = f2bf(v);
                }
            }
        }
    } else {
        ushort* C = (ushort*)Cout;
        float bb[4];
#pragma unroll
        for (int j = 0; j < 4; ++j) bb[j] = bias0[n0 + wn + j * 16 + l16];
#pragma unroll
        for (int i = 0; i < 4; ++i) {
            int mbase = m0 + wm + i * 16 + quad * 4;
#pragma unroll
            for (int r = 0; r < 4; ++r) {
                int m = mbase + r;
                int s = m & 63, b = m >> 6;
                ushort* crow = C + ((size_t)(s * 64 + b)) * 2048;
#pragma unroll
                for (int j = 0; j < 4; ++j)
                    crow[n0 + wn + j * 16 + l16] = f2bf(acc[i][j][r] + bb[j]);
            }
        }
    }
}

// dots[bs][p] = v_bf16[bs][:] . proto_bf[p][:] (proto padded to 32 rows)
__global__ __launch_bounds__(256) void k_dot(const ushort* __restrict__ v_bf,
                                             const ushort* __restrict__ proto_bf,
                                             float* __restrict__ dots)
{
    const int tid = threadIdx.x;
    const int lane = tid & 63, w = tid >> 6;
    const int quad = lane >> 4, l16 = lane & 15;
    const int r0 = blockIdx.x * 64 + w * 16;

    f32x4 acc[2] = {};
    const ushort* arow = v_bf + (size_t)(r0 + l16) * 2048 + quad * 8;
    const ushort* b0p = proto_bf + (size_t)l16 * 2048 + quad * 8;
    const ushort* b1p = proto_bf + (size_t)(16 + l16) * 2048 + quad * 8;
#pragma unroll 8
    for (int kk = 0; kk < 64; ++kk) {
        short8 af = *(const short8*)(arow + kk * 32);
        short8 bf0 = *(const short8*)(b0p + kk * 32);
        short8 bf1 = *(const short8*)(b1p + kk * 32);
        acc[0] = __builtin_amdgcn_mfma_f32_16x16x32_bf16(af, bf0, acc[0], 0, 0, 0);
        acc[1] = __builtin_amdgcn_mfma_f32_16x16x32_bf16(af, bf1, acc[1], 0, 0, 0);
    }
#pragma unroll
    for (int t = 0; t < 2; ++t)
#pragma unroll
        for (int r = 0; r < 4; ++r)
            dots[(size_t)(r0 + quad * 4 + r) * 32 + t * 16 + l16] = acc[t][r];
}

// per-row |v|^2 and gate-logit partials. grid 1024 blocks x 4 rows.
__global__ __launch_bounds__(256) void k_rowstats(const float* __restrict__ v_feat,
                                                  const float* __restrict__ W_gate,
                                                  float* __restrict__ n2,
                                                  float* __restrict__ g_logit)
{
    const int lane = threadIdx.x & 63, w = threadIdx.x >> 6;
    const int bs = blockIdx.x * 4 + w;
    const float* vr = v_feat + (size_t)bs * 2048;
    float a = 0.f, g = 0.f;
#pragma unroll
    for (int i = 0; i < 8; ++i) {
        float4 x = ((const float4*)vr)[i * 64 + lane];
        float4 wg = ((const float4*)W_gate)[i * 64 + lane];
        a += x.x * x.x + x.y * x.y + x.z * x.z + x.w * x.w;
        g += x.x * wg.x + x.y * wg.y + x.z * wg.z + x.w * wg.w;
    }
#pragma unroll
    for (int o = 32; o > 0; o >>= 1) { a += __shfl_down(a, o); g += __shfl_down(g, o); }
    if (lane == 0) {
        n2[bs] = a;
        atomicAdd(&g_logit[bs >> 6], g);
    }
}

// p2[p] = |proto[p]|^2. grid 20 x 64.
__global__ __launch_bounds__(64) void k_p2(const float* __restrict__ proto,
                                           float* __restrict__ p2)
{
    const int lane = threadIdx.x;
    const float* pr = proto + (size_t)blockIdx.x * 2048;
    float a = 0.f;
#pragma unroll
    for (int i = 0; i < 8; ++i) {
        float4 x = ((const float4*)pr)[i * 64 + lane];
        a += x.x * x.x + x.y * x.y + x.z * x.z + x.w * x.w;
    }
#pragma unroll
    for (int o = 32; o > 0; o >>= 1) a += __shfl_down(a, o);
    if (lane == 0) p2[blockIdx.x] = a;
}

// dd_logit[b] = sum_{s,p} log((d+1)/(d+1e-8)) * W_dd[s*20+p]. grid 64.
__global__ __launch_bounds__(256) void k_dd(const float* __restrict__ dots,
                                            const float* __restrict__ n2,
                                            const float* __restrict__ p2,
                                            const float* __restrict__ W_dd,
                                            float* __restrict__ dd_logit)
{
    __shared__ float red[4];
    const int b = blockIdx.x;
    const int tid = threadIdx.x, lane = tid & 63, w = tid >> 6;
    float acc = 0.f;
    for (int u = tid; u < 1280; u += 256) {
        int s = u / 20, p = u - s * 20;
        int bs = b * 64 + s;
        float d = n2[bs] - 2.f * dots[(size_t)bs * 32 + p] + p2[p];
        acc += logf((d + 1.0f) / (d + 1e-8f)) * W_dd[s * 20 + p];
    }
#pragma unroll
    for (int o = 32; o > 0; o >>= 1) acc += __shfl_down(acc, o);
    if (lane == 0) red[w] = acc;
    __syncthreads();
    if (tid == 0) dd_logit[b] = red[0] + red[1] + red[2] + red[3];
}

// ---------------------------------------------------------------------------
// Persistent LSTM. Block bn owns n' in [bn*32, +32) (j in [8bn, 8bn+8)).
// h layout (block-major, line-owned): elem(j,b) = (j>>3)*512 + b*8 + (j&7).
// Rotating slots: hbuf + s*32768 is h after s steps (slot 0 = zeros).
// Consumer h loads: PLAIN dwordx4 (fresh addresses -> L2 miss -> LLC, fast,
// pipelined, XCD-shared). Producer h stores: sc1 relaxed atomics (LLC
// write-through). Barrier: per-block monotonic flag, relaxed poll (round 6).
// ---------------------------------------------------------------------------
__global__ __launch_bounds__(256) void k_lstm_persist(
    const ushort* __restrict__ xg,       // [s][b][n'] bf16
    const ushort* __restrict__ Whr,      // [n'=2048][k=512] bf16
    ushort* __restrict__ hbuf,           // 65 slots x 32768 elems (slot0 zeroed)
    int* __restrict__ flags,             // [64] pre-zeroed, monotonic
    const float* __restrict__ W_dec, const float* __restrict__ b_dec,
    const float* __restrict__ dd_logit, const float* __restrict__ b_dd,
    const float* __restrict__ g_logit, const float* __restrict__ b_gate,
    float* __restrict__ out)
{
    __shared__ ushort Bs[16384];         // 32 KB weights, fragment-linear
    __shared__ float fred[4][64];
    const int tid = threadIdx.x;
    const int lane = tid & 63, w = tid >> 6;
    const int quad = lane >> 4, l16 = lane & 15;
    const int bn = blockIdx.x;
    const int n0 = bn * 32;

    // stage weights into fragment-linear LDS (conflict-free ds_read_b128)
    for (int c = tid; c < 2048; c += 256) {
        int row = c >> 6, chunk = c & 63;               // chunk = 16B unit in row
        int f = ((row >> 4) * 16 + (chunk >> 2)) * 4 + (chunk & 3);
        uint4 v = *(const uint4*)(Whr + (size_t)(n0 + row) * 512 + chunk * 8);
        *(uint4*)&Bs[(f * 16 + (row & 15)) * 8] = v;
    }
    __syncthreads();

    const int b_glob = w * 16 + l16;     // this lane's batch row
    float c0r = 0.f, c1r = 0.f;

    for (int s = 0; s < 64; ++s) {
        // xg prefetch (plain loads; xg immutable, L2-cacheable)
        const ushort* xrow = xg + ((size_t)(s * 64 + b_glob)) * 2048 + n0;
        ushort4 xa = *(const ushort4*)(xrow + quad * 4);
        ushort4 xb = *(const ushort4*)(xrow + 16 + quad * 4);

        if (s > 0) {
            if (tid < 64) {
                while (__hip_atomic_load(&flags[tid], __ATOMIC_RELAXED,
                                         __HIP_MEMORY_SCOPE_AGENT) < s) {}
            }
            __syncthreads();    // also a compiler barrier: h loads can't hoist
        }
        // consumer base: region (k-chunk owner) = kk*4+quad at stride 512
        const ushort* hin = hbuf + (size_t)s * 32768 + b_glob * 8 + quad * 512;
        ushort* hout = hbuf + (size_t)(s + 1) * 32768;

        f32x4 a0a = {}, a0b = {}, a1a = {}, a1b = {};
#pragma unroll
        for (int kk = 0; kk < 8; ++kk) {
            short8 hb0 = *(const short8*)(hin + kk * 2048);            // k = kk*32+quad*8
            short8 hb1 = *(const short8*)(hin + kk * 2048 + 16384);    // k = (kk+8)*32+quad*8
            short8 w0a = *(const short8*)&Bs[(((kk) * 4 + quad) * 16 + l16) * 8];
            short8 w0b = *(const short8*)&Bs[(((kk + 8) * 4 + quad) * 16 + l16) * 8];
            short8 w1a = *(const short8*)&Bs[(((16 + kk) * 4 + quad) * 16 + l16) * 8];
            short8 w1b = *(const short8*)&Bs[(((24 + kk) * 4 + quad) * 16 + l16) * 8];
            a0a = __builtin_amdgcn_mfma_f32_16x16x32_bf16(w0a, hb0, a0a, 0, 0, 0);
            a0b = __builtin_amdgcn_mfma_f32_16x16x32_bf16(w0b, hb1, a0b, 0, 0, 0);
            a1a = __builtin_amdgcn_mfma_f32_16x16x32_bf16(w1a, hb0, a1a, 0, 0, 0);
            a1b = __builtin_amdgcn_mfma_f32_16x16x32_bf16(w1b, hb1, a1b, 0, 0, 0);
        }
        f32x4 g0 = a0a + a0b;   // n' = n0 + quad*4 + reg  -> reg = gate, j = 8bn+quad
        f32x4 g1 = a1a + a1b;   // n' = n0 + 16 + quad*4 + reg -> j = 8bn+4+quad
        {
            float gi = sigm(g0[0] + bf2f(xa.x));
            float gf = sigm(g0[1] + bf2f(xa.y));
            float go = sigm(g0[2] + bf2f(xa.z));
            float gg = tanh_fast(g0[3] + bf2f(xa.w));
            c0r = gf * c0r + gi * gg;
            __hip_atomic_store(&hout[bn * 512 + b_glob * 8 + quad],
                               f2bf(go * c0r), __ATOMIC_RELAXED, __HIP_MEMORY_SCOPE_AGENT);
        }
        {
            float gi = sigm(g1[0] + bf2f(xb.x));
            float gf = sigm(g1[1] + bf2f(xb.y));
            float go = sigm(g1[2] + bf2f(xb.z));
            float gg = tanh_fast(g1[3] + bf2f(xb.w));
            c1r = gf * c1r + gi * gg;
            __hip_atomic_store(&hout[bn * 512 + b_glob * 8 + 4 + quad],
                               f2bf(go * c1r), __ATOMIC_RELAXED, __HIP_MEMORY_SCOPE_AGENT);
        }
        __syncthreads();        // pre-barrier waitcnt drains every wave's sc1 stores
        if (tid == 0)
            __hip_atomic_store(&flags[bn], s + 1, __ATOMIC_RELAXED,
                               __HIP_MEMORY_SCOPE_AGENT);
    }

    // final head: h(64) in slot 64 (fresh addresses -> plain loads safe)
    if (bn == 0) {
        if (tid < 64) {
            while (__hip_atomic_load(&flags[tid], __ATOMIC_RELAXED,
                                     __HIP_MEMORY_SCOPE_AGENT) < 64) {}
        }
        __syncthreads();
        const ushort* hb = hbuf + (size_t)64 * 32768;
        int b = tid & 63, part = tid >> 6;           // each wave does 128 j's
        float acc = 0.f;
#pragma unroll 4
        for (int jj = 0; jj < 128; jj += 4) {
            int j = part * 128 + jj;
            ull u = *(const ull*)(hb + (j >> 3) * 512 + b * 8 + (j & 7));
            acc += bf2f((ushort)u) * W_dec[j]
                 + bf2f((ushort)(u >> 16)) * W_dec[j + 1]
                 + bf2f((ushort)(u >> 32)) * W_dec[j + 2]
                 + bf2f((ushort)(u >> 48)) * W_dec[j + 3];
        }
        fred[part][b] = acc;
        __syncthreads();
        if (tid < 64) {
            float a = fred[0][tid] + fred[1][tid] + fred[2][tid] + fred[3][tid];
            float output = sigm(a + b_dec[0]);
            float gate   = sigm(g_logit[tid] * (1.0f / 64.f) + b_gate[0]);
            float ddp    = sigm(dd_logit[tid] + b_dd[0]);
            out[tid] = output * gate + ddp * (1.f - gate);
        }
    }
}

extern "C" void kernel_launch(void* const* d_in, const int* in_sizes, int n_in,
                              void* d_out, int out_size, void* d_ws, size_t ws_size,
                              hipStream_t stream) {
    const float* v_feat   = (const float*)d_in[0];
    const int*   category = (const int*)d_in[1];
    const float* W_enc    = (const float*)d_in[2];
    const float* b_enc    = (const float*)d_in[3];
    const float* Wx       = (const float*)d_in[4];
    const float* bx       = (const float*)d_in[5];
    const float* Wh       = (const float*)d_in[6];
    const float* bh       = (const float*)d_in[7];
    const float* cat_emb  = (const float*)d_in[8];
    const float* W_dec    = (const float*)d_in[9];
    const float* b_dec    = (const float*)d_in[10];
    const float* proto    = (const float*)d_in[11];
    const float* W_dd     = (const float*)d_in[12];
    const float* b_dd     = (const float*)d_in[13];
    const float* W_gate   = (const float*)d_in[14];
    const float* b_gate   = (const float*)d_in[15];
    float* out = (float*)d_out;

    char* ws = (char*)d_ws;
    ushort* xg       = (ushort*)(ws + 0);          // 16 MB bf16 [s][b][n']
    ushort* v_bf16   = (ushort*)(ws + 0);          // 16 MB (dead before GEMM2 writes xg)
    ushort* fuse     = (ushort*)(ws + 16777216);   // 4 MB bf16 [4096][512]
    ushort* Whr      = (ushort*)(ws + 20971520);   // 2 MB bf16 [2048][512] (n' rows)
    ushort* Wenc_t   = (ushort*)(ws + 23068672);   // 2 MB bf16 [512][2048]
    ushort* Wx_t     = (ushort*)(ws + 25165824);   // 2 MB bf16 [2048][512] (n' rows)
    ushort* proto_bf = (ushort*)(ws + 27262976);   // 128 KB [32][2048]
    float*  dots     = (float*)(ws + 27394048);    // 512 KB [4096][32]
    float*  n2       = (float*)(ws + 27918336);    // 16 KB
    float*  p2       = (float*)(ws + 27934720);    // 512 B
    float*  bxh      = (float*)(ws + 27935232);    // 8 KB
    int*    flags    = (int*)(ws + 27943424);      // 1 KB (64 words used)
    float*  dd_logit = (float*)(ws + 27944448);    // 256 B
    float*  g_logit  = (float*)(ws + 27944704);    // 256 B
    ushort* hbuf     = (ushort*)(ws + 27944960);   // 65 x 64 KB = 4.06 MB rotating h

    hipMemsetAsync(proto_bf, 0, 131072, stream);
    hipMemsetAsync(flags, 0, 1536, stream);        // flags + dd_logit + g_logit
    hipMemsetAsync(hbuf, 0, 65536, stream);        // slot 0 = h(0) = 0

    k_f32_to_bf16<<<8192, 256, 0, stream>>>(v_feat, v_bf16);
    k_f32_to_bf16<<<40, 256, 0, stream>>>(proto, proto_bf);
    k_bias<<<8, 256, 0, stream>>>(bx, bh, bxh);
    k_transpose_bf16<<<dim3(16, 64), 256, 0, stream>>>(W_enc, Wenc_t, 2048, 512, 0);
    k_transpose_bf16<<<dim3(64, 16), 256, 0, stream>>>(Wx, Wx_t, 512, 2048, 1);
    k_transpose_bf16<<<dim3(64, 16), 256, 0, stream>>>(Wh, Whr, 512, 2048, 1);

    k_gemm_mfma<<<dim3(4, 32), 256, 0, stream>>>(v_bf16, Wenc_t, 4096, 512, 2048,
                                                 b_enc, cat_emb, category, fuse, 0);
    k_dot<<<64, 256, 0, stream>>>(v_bf16, proto_bf, dots);
    k_rowstats<<<1024, 256, 0, stream>>>(v_feat, W_gate, n2, g_logit);
    k_p2<<<20, 64, 0, stream>>>(proto, p2);
    k_dd<<<64, 256, 0, stream>>>(dots, n2, p2, W_dd, dd_logit);

    k_gemm_mfma<<<dim3(16, 32), 256, 0, stream>>>(fuse, Wx_t, 4096, 2048, 512,
                                                  bxh, nullptr, nullptr, xg, 1);

    k_lstm_persist<<<64, 256, 0, stream>>>(xg, Whr, hbuf, flags,
                                           W_dec, b_dec, dd_logit, b_dd,
                                           g_logit, b_gate, out);
}